// Round 1
// baseline (553.970 us; speedup 1.0000x reference)
//
#include <hip/hip_runtime.h>
#include <math.h>

#define IMH 512
#define IMW 512
#define NIMG 64
#define NPIX (IMH*IMW)
#define NELEM (NPIX*3)
#define CXF 255.5f
#define CYF 255.5f
#define ENHF 1.45f
#define INVENHF (1.0f/1.45f)
#define FILLF 0.5f
#define MBPI 64   // reduction blocks per image

struct F3 { float x, y, z; };

__device__ __forceinline__ F3 mk3(float v){ F3 r; r.x=v; r.y=v; r.z=v; return r; }

__device__ __forceinline__ F3 ldpix(const float* __restrict__ im, int y, int x){
  const float* p = im + (y*IMW + x)*3;
  F3 r; r.x=p[0]; r.y=p[1]; r.z=p[2]; return r;
}

__device__ __forceinline__ F3 clip01(F3 v){
  F3 r;
  r.x = fminf(fmaxf(v.x, 0.f), 1.f);
  r.y = fminf(fmaxf(v.y, 0.f), 1.f);
  r.z = fminf(fmaxf(v.z, 0.f), 1.f);
  return r;
}

// inverse-affine coefficients for ops 0..4 (rotate, shear_x, shear_y, trans_x, trans_y)
__device__ __forceinline__ void affine_params(int op, float s,
    float& a, float& b, float& tx, float& c, float& d, float& ty){
  a = 1.f; b = 0.f; tx = 0.f; c = 0.f; d = 1.f; ty = 0.f;
  if (op == 0){            // rotate by s*15deg: cos even, sin odd -> fold sign
    a = 0.96592582628907f; b = s * 0.25881904510252f; c = -b; d = a;
  } else if (op == 1){     // shear_x
    b = -s * 0.15f;
  } else if (op == 2){     // shear_y
    c = -s * 0.15f;
  } else if (op == 3){     // trans_x: t = s*0.15*512
    tx = -s * 76.8f;
  } else if (op == 4){     // trans_y
    ty = -s * 76.8f;
  }
}

// bilinear sample of the RAW input image with FILL for out-of-bounds corners
__device__ __forceinline__ F3 bilin_img(const float* __restrict__ im, float xi, float yi){
  float x0 = floorf(xi), y0 = floorf(yi);
  float wx = xi - x0, wy = yi - y0;
  F3 acc = mk3(0.f);
  #pragma unroll
  for (int cidx = 0; cidx < 4; cidx++){
    int dx = cidx & 1, dy = cidx >> 1;
    float xx = x0 + (float)dx, yy = y0 + (float)dy;
    float w = (dx ? wx : (1.f - wx)) * (dy ? wy : (1.f - wy));
    F3 v;
    if (xx >= 0.f && xx <= (float)(IMW-1) && yy >= 0.f && yy <= (float)(IMH-1))
      v = ldpix(im, (int)yy, (int)xx);
    else
      v = mk3(FILLF);
    acc.x += w * v.x; acc.y += w * v.y; acc.z += w * v.z;
  }
  return acc;
}

// value of the layer-0 output at integer pixel (x,y), computed on the fly
__device__ F3 eval0(const float* __restrict__ im, int op, float s, float mean0, int x, int y){
  if (op < 5){
    float a,b,tx,c,d,ty; affine_params(op, s, a, b, tx, c, d, ty);
    float fx = (float)x - CXF, fy = (float)y - CYF;
    return bilin_img(im, a*fx + b*fy + tx + CXF, c*fx + d*fy + ty + CYF);
  }
  F3 v = ldpix(im, y, x);
  float f = (s > 0.f) ? ENHF : INVENHF;
  if (op == 5){           // brightness: clip(f * img)
    F3 r; r.x = f*v.x; r.y = f*v.y; r.z = f*v.z; return clip01(r);
  }
  if (op == 6){           // contrast: clip(mean + f*(img-mean))
    F3 r;
    r.x = mean0 + f*(v.x - mean0);
    r.y = mean0 + f*(v.y - mean0);
    r.z = mean0 + f*(v.z - mean0);
    return clip01(r);
  }
  // sharpness: clip(smooth + f*(img - smooth)), 3x3 kernel [[1,1,1],[1,5,1],[1,1,1]]/13, edge pad
  F3 sm; sm.x = (5.f/13.f)*v.x; sm.y = (5.f/13.f)*v.y; sm.z = (5.f/13.f)*v.z;
  #pragma unroll
  for (int dy = -1; dy <= 1; dy++){
    #pragma unroll
    for (int dx = -1; dx <= 1; dx++){
      if (dx == 0 && dy == 0) continue;
      int yy = min(max(y + dy, 0), IMH-1);
      int xx = min(max(x + dx, 0), IMW-1);
      F3 q = ldpix(im, yy, xx);
      sm.x += (1.f/13.f)*q.x; sm.y += (1.f/13.f)*q.y; sm.z += (1.f/13.f)*q.z;
    }
  }
  F3 r;
  r.x = sm.x + f*(v.x - sm.x);
  r.y = sm.y + f*(v.y - sm.y);
  r.z = sm.z + f*(v.z - sm.z);
  return clip01(r);
}

// bilinear sample of the layer-0 OUTPUT (on-the-fly eval0) with FILL out of bounds
__device__ F3 bilin_eval0(const float* __restrict__ im, int op0, float s0, float mean0,
                          float xi, float yi){
  float x0 = floorf(xi), y0 = floorf(yi);
  float wx = xi - x0, wy = yi - y0;
  F3 acc = mk3(0.f);
  #pragma unroll
  for (int cidx = 0; cidx < 4; cidx++){
    int dx = cidx & 1, dy = cidx >> 1;
    float xx = x0 + (float)dx, yy = y0 + (float)dy;
    float w = (dx ? wx : (1.f - wx)) * (dy ? wy : (1.f - wy));
    F3 v;
    if (xx >= 0.f && xx <= (float)(IMW-1) && yy >= 0.f && yy <= (float)(IMH-1))
      v = eval0(im, op0, s0, mean0, (int)xx, (int)yy);
    else
      v = mk3(FILLF);
    acc.x += w * v.x; acc.y += w * v.y; acc.z += w * v.z;
  }
  return acc;
}

__device__ __forceinline__ float block_reduce(float v){
  #pragma unroll
  for (int off = 32; off > 0; off >>= 1) v += __shfl_down(v, off, 64);
  __shared__ float sm[4];
  int lane = threadIdx.x & 63, wid = threadIdx.x >> 6;
  if (lane == 0) sm[wid] = v;
  __syncthreads();
  float r = 0.f;
  if (threadIdx.x == 0) r = sm[0] + sm[1] + sm[2] + sm[3];
  return r;
}

// mean of raw input image (only for images whose layer-0 op is contrast)
__global__ __launch_bounds__(256) void mean0_kernel(const float* __restrict__ images,
    const int* __restrict__ ops, float* __restrict__ means){
  int img = blockIdx.x / MBPI;
  if (ops[2*img] != 6) return;
  const float* im = images + (size_t)img * NELEM;
  float s = 0.f;
  for (int i = (blockIdx.x % MBPI)*256 + threadIdx.x; i < NELEM; i += MBPI*256)
    s += im[i];
  s = block_reduce(s);
  if (threadIdx.x == 0) atomicAdd(&means[2*img], s * (1.0f/(float)NELEM));
}

// mean of layer-0 output (only for images whose layer-1 op is contrast)
__global__ __launch_bounds__(256) void mean1_kernel(const float* __restrict__ images,
    const int* __restrict__ ops, const int* __restrict__ signs, float* __restrict__ means){
  int img = blockIdx.x / MBPI;
  if (ops[2*img + 1] != 6) return;
  int op0 = ops[2*img];
  float s0 = signs[2*img] ? 1.f : -1.f;
  float mean0 = means[2*img];
  const float* im = images + (size_t)img * NELEM;
  float s = 0.f;
  for (int p = (blockIdx.x % MBPI)*256 + threadIdx.x; p < NPIX; p += MBPI*256){
    F3 v = eval0(im, op0, s0, mean0, p & (IMW-1), p >> 9);
    s += v.x + v.y + v.z;
  }
  s = block_reduce(s);
  if (threadIdx.x == 0) atomicAdd(&means[2*img + 1], s * (1.0f/(float)NELEM));
}

// fused layer1(layer0(img)) per output pixel
__global__ __launch_bounds__(256) void apply_kernel(const float* __restrict__ images,
    const int* __restrict__ ops, const int* __restrict__ signs,
    const float* __restrict__ means, float* __restrict__ out){
  int img = blockIdx.x >> 10;                       // 1024 blocks/image
  int pix = ((blockIdx.x & 1023) << 8) | threadIdx.x;
  int x = pix & (IMW-1), y = pix >> 9;
  const float* im = images + (size_t)img * NELEM;
  int op0 = ops[2*img], op1 = ops[2*img + 1];
  float s0 = signs[2*img]     ? 1.f : -1.f;
  float s1 = signs[2*img + 1] ? 1.f : -1.f;
  float mean0 = means[2*img], mean1 = means[2*img + 1];

  F3 r;
  if (op1 < 5){
    float a,b,tx,c,d,ty; affine_params(op1, s1, a, b, tx, c, d, ty);
    float fx = (float)x - CXF, fy = (float)y - CYF;
    r = bilin_eval0(im, op0, s0, mean0, a*fx + b*fy + tx + CXF, c*fx + d*fy + ty + CYF);
  } else {
    F3 v = eval0(im, op0, s0, mean0, x, y);
    float f = (s1 > 0.f) ? ENHF : INVENHF;
    if (op1 == 5){
      r.x = f*v.x; r.y = f*v.y; r.z = f*v.z;
      r = clip01(r);
    } else if (op1 == 6){
      r.x = mean1 + f*(v.x - mean1);
      r.y = mean1 + f*(v.y - mean1);
      r.z = mean1 + f*(v.z - mean1);
      r = clip01(r);
    } else {   // sharpness over layer-0 output
      F3 sm; sm.x = (5.f/13.f)*v.x; sm.y = (5.f/13.f)*v.y; sm.z = (5.f/13.f)*v.z;
      #pragma unroll
      for (int dy = -1; dy <= 1; dy++){
        #pragma unroll
        for (int dx = -1; dx <= 1; dx++){
          if (dx == 0 && dy == 0) continue;
          int yy = min(max(y + dy, 0), IMH-1);
          int xx = min(max(x + dx, 0), IMW-1);
          F3 q = eval0(im, op0, s0, mean0, xx, yy);
          sm.x += (1.f/13.f)*q.x; sm.y += (1.f/13.f)*q.y; sm.z += (1.f/13.f)*q.z;
        }
      }
      r.x = sm.x + f*(v.x - sm.x);
      r.y = sm.y + f*(v.y - sm.y);
      r.z = sm.z + f*(v.z - sm.z);
      r = clip01(r);
    }
  }
  float* o = out + ((size_t)img * NPIX + pix) * 3;
  o[0] = r.x; o[1] = r.y; o[2] = r.z;
}

extern "C" void kernel_launch(void* const* d_in, const int* in_sizes, int n_in,
                              void* d_out, int out_size, void* d_ws, size_t ws_size,
                              hipStream_t stream){
  const float* images = (const float*)d_in[0];
  const int*   ops    = (const int*)d_in[1];
  const int*   signs  = (const int*)d_in[2];
  float* out   = (float*)d_out;
  float* means = (float*)d_ws;   // 2 floats per image: [mean0, mean1]

  // ws is poisoned 0xAA before every launch -> zero the accumulators (memset node is capture-safe)
  hipMemsetAsync(means, 0, 2*NIMG*sizeof(float), stream);
  mean0_kernel<<<NIMG*MBPI, 256, 0, stream>>>(images, ops, means);
  mean1_kernel<<<NIMG*MBPI, 256, 0, stream>>>(images, ops, signs, means);
  apply_kernel<<<NIMG*1024, 256, 0, stream>>>(images, ops, signs, means, out);
}

// Round 2
// 496.575 us; speedup vs baseline: 1.1156x; 1.1156x over previous
//
#include <hip/hip_runtime.h>
#include <math.h>

#define IMH 512
#define IMW 512
#define NIMG 64
#define NPIX (IMH*IMW)
#define NELEM (NPIX*3)
#define CXF 255.5f
#define CYF 255.5f
#define ENHF 1.45f
#define INVENHF (1.0f/1.45f)
#define FILLF 0.5f
#define MBPI 64    // reduction blocks per image
#define TW 64      // output tile width per block
#define TH 16      // output tile height per block
#define MAXLDS 2560  // max staged pixels (worst case rotate: 69x35 = 2415)

struct F3 { float x, y, z; };

__device__ __forceinline__ F3 mk3(float v){ F3 r; r.x=v; r.y=v; r.z=v; return r; }

__device__ __forceinline__ F3 ldpix(const float* __restrict__ im, int y, int x){
  const float* p = im + (y*IMW + x)*3;
  F3 r; r.x=p[0]; r.y=p[1]; r.z=p[2]; return r;
}

__device__ __forceinline__ F3 clip01(F3 v){
  F3 r;
  r.x = fminf(fmaxf(v.x, 0.f), 1.f);
  r.y = fminf(fmaxf(v.y, 0.f), 1.f);
  r.z = fminf(fmaxf(v.z, 0.f), 1.f);
  return r;
}

// inverse-affine coefficients for ops 0..4 (rotate, shear_x, shear_y, trans_x, trans_y)
__device__ __forceinline__ void affine_params(int op, float s,
    float& a, float& b, float& tx, float& c, float& d, float& ty){
  a = 1.f; b = 0.f; tx = 0.f; c = 0.f; d = 1.f; ty = 0.f;
  if (op == 0){            // rotate by s*15deg: cos even, sin odd -> fold sign
    a = 0.96592582628907f; b = s * 0.25881904510252f; c = -b; d = a;
  } else if (op == 1){     // shear_x
    b = -s * 0.15f;
  } else if (op == 2){     // shear_y
    c = -s * 0.15f;
  } else if (op == 3){     // trans_x: t = s*0.15*512
    tx = -s * 76.8f;
  } else if (op == 4){     // trans_y
    ty = -s * 76.8f;
  }
}

// bilinear sample of the RAW input image with FILL for out-of-bounds corners
__device__ __forceinline__ F3 bilin_img(const float* __restrict__ im, float xi, float yi){
  float x0 = floorf(xi), y0 = floorf(yi);
  float wx = xi - x0, wy = yi - y0;
  F3 acc = mk3(0.f);
  #pragma unroll
  for (int cidx = 0; cidx < 4; cidx++){
    int dx = cidx & 1, dy = cidx >> 1;
    float xx = x0 + (float)dx, yy = y0 + (float)dy;
    float w = (dx ? wx : (1.f - wx)) * (dy ? wy : (1.f - wy));
    F3 v;
    if (xx >= 0.f && xx <= (float)(IMW-1) && yy >= 0.f && yy <= (float)(IMH-1))
      v = ldpix(im, (int)yy, (int)xx);
    else
      v = mk3(FILLF);
    acc.x += w * v.x; acc.y += w * v.y; acc.z += w * v.z;
  }
  return acc;
}

// value of the layer-0 output at integer pixel (x,y), computed on the fly
__device__ F3 eval0(const float* __restrict__ im, int op, float s, float mean0, int x, int y){
  if (op < 5){
    float a,b,tx,c,d,ty; affine_params(op, s, a, b, tx, c, d, ty);
    float fx = (float)x - CXF, fy = (float)y - CYF;
    return bilin_img(im, a*fx + b*fy + tx + CXF, c*fx + d*fy + ty + CYF);
  }
  F3 v = ldpix(im, y, x);
  float f = (s > 0.f) ? ENHF : INVENHF;
  if (op == 5){           // brightness: clip(f * img)
    F3 r; r.x = f*v.x; r.y = f*v.y; r.z = f*v.z; return clip01(r);
  }
  if (op == 6){           // contrast: clip(mean + f*(img-mean))
    F3 r;
    r.x = mean0 + f*(v.x - mean0);
    r.y = mean0 + f*(v.y - mean0);
    r.z = mean0 + f*(v.z - mean0);
    return clip01(r);
  }
  // sharpness: clip(smooth + f*(img - smooth)), 3x3 kernel [[1,1,1],[1,5,1],[1,1,1]]/13, edge pad
  F3 sm; sm.x = (5.f/13.f)*v.x; sm.y = (5.f/13.f)*v.y; sm.z = (5.f/13.f)*v.z;
  #pragma unroll
  for (int dy = -1; dy <= 1; dy++){
    #pragma unroll
    for (int dx = -1; dx <= 1; dx++){
      if (dx == 0 && dy == 0) continue;
      int yy = min(max(y + dy, 0), IMH-1);
      int xx = min(max(x + dx, 0), IMW-1);
      F3 q = ldpix(im, yy, xx);
      sm.x += (1.f/13.f)*q.x; sm.y += (1.f/13.f)*q.y; sm.z += (1.f/13.f)*q.z;
    }
  }
  F3 r;
  r.x = sm.x + f*(v.x - sm.x);
  r.y = sm.y + f*(v.y - sm.y);
  r.z = sm.z + f*(v.z - sm.z);
  return clip01(r);
}

__device__ __forceinline__ float block_reduce(float v){
  #pragma unroll
  for (int off = 32; off > 0; off >>= 1) v += __shfl_down(v, off, 64);
  __shared__ float sm[4];
  int lane = threadIdx.x & 63, wid = threadIdx.x >> 6;
  if (lane == 0) sm[wid] = v;
  __syncthreads();
  float r = 0.f;
  if (threadIdx.x == 0) r = sm[0] + sm[1] + sm[2] + sm[3];
  return r;
}

// mean of raw input image (only for images whose layer-0 op is contrast)
__global__ __launch_bounds__(256) void mean0_kernel(const float* __restrict__ images,
    const int* __restrict__ ops, float* __restrict__ means){
  int img = blockIdx.x / MBPI;
  if (ops[2*img] != 6) return;
  const float* im = images + (size_t)img * NELEM;
  float s = 0.f;
  for (int i = (blockIdx.x % MBPI)*256 + threadIdx.x; i < NELEM; i += MBPI*256)
    s += im[i];
  s = block_reduce(s);
  if (threadIdx.x == 0) atomicAdd(&means[2*img], s * (1.0f/(float)NELEM));
}

// mean of layer-0 output (only for images whose layer-1 op is contrast)
__global__ __launch_bounds__(256) void mean1_kernel(const float* __restrict__ images,
    const int* __restrict__ ops, const int* __restrict__ signs, float* __restrict__ means){
  int img = blockIdx.x / MBPI;
  if (ops[2*img + 1] != 6) return;
  int op0 = ops[2*img];
  float s0 = signs[2*img] ? 1.f : -1.f;
  float mean0 = means[2*img];
  const float* im = images + (size_t)img * NELEM;
  float s = 0.f;
  for (int p = (blockIdx.x % MBPI)*256 + threadIdx.x; p < NPIX; p += MBPI*256){
    F3 v = eval0(im, op0, s0, mean0, p & (IMW-1), p >> 9);
    s += v.x + v.y + v.z;
  }
  s = block_reduce(s);
  if (threadIdx.x == 0) atomicAdd(&means[2*img + 1], s * (1.0f/(float)NELEM));
}

// Tiled fused kernel: stage layer-0 output over the needed bbox into LDS once,
// then resample/smooth it for layer-1. 4 px/thread, packed float4 stores.
__global__ __launch_bounds__(256) void apply_kernel(const float* __restrict__ images,
    const int* __restrict__ ops, const int* __restrict__ signs,
    const float* __restrict__ means, float* __restrict__ out){
  int img  = blockIdx.x >> 8;            // 256 tiles per image (8 x 32)
  int tile = blockIdx.x & 255;
  int tx0 = (tile & 7) * TW;
  int ty0 = (tile >> 3) * TH;
  const float* im = images + (size_t)img * NELEM;
  int op0 = ops[2*img], op1 = ops[2*img + 1];
  float s0 = signs[2*img]     ? 1.f : -1.f;
  float s1 = signs[2*img + 1] ? 1.f : -1.f;
  float mean0 = means[2*img], mean1 = means[2*img + 1];

  // ---- bbox of layer-0 pixels needed by this tile's layer-1 op ----
  float a1=1.f,b1=0.f,txx=0.f,c1=0.f,d1=1.f,tyy=0.f;
  int bx0, by0, bx1, by1;
  if (op1 < 5){
    affine_params(op1, s1, a1, b1, txx, c1, d1, tyy);
    float xmin = 1e30f, xmax = -1e30f, ymin = 1e30f, ymax = -1e30f;
    #pragma unroll
    for (int i = 0; i < 4; i++){
      float fx = (float)(tx0 + (i & 1) * (TW - 1)) - CXF;
      float fy = (float)(ty0 + (i >> 1) * (TH - 1)) - CYF;
      float xi = a1*fx + b1*fy + txx + CXF;
      float yi = c1*fx + d1*fy + tyy + CYF;
      xmin = fminf(xmin, xi); xmax = fmaxf(xmax, xi);
      ymin = fminf(ymin, yi); ymax = fmaxf(ymax, yi);
    }
    bx0 = (int)floorf(xmin) - 1; bx1 = (int)floorf(xmax) + 2;
    by0 = (int)floorf(ymin) - 1; by1 = (int)floorf(ymax) + 2;
  } else if (op1 == 7){                  // sharpness needs +-1 halo
    bx0 = tx0 - 1; bx1 = tx0 + TW; by0 = ty0 - 1; by1 = ty0 + TH;
  } else {                               // brightness/contrast: tile only
    bx0 = tx0; bx1 = tx0 + TW - 1; by0 = ty0; by1 = ty0 + TH - 1;
  }
  bx0 = max(bx0, 0); by0 = max(by0, 0);
  bx1 = min(bx1, IMW - 1); by1 = min(by1, IMH - 1);
  int bw = bx1 - bx0 + 1, bh = by1 - by0 + 1;
  int nstage = (bw > 0 && bh > 0) ? bw * bh : 0;

  // ---- stage eval0 over bbox into LDS (each layer-0 pixel computed ONCE) ----
  __shared__ float lds[MAXLDS * 3];
  for (int idx = threadIdx.x; idx < nstage; idx += 256){
    int iy = idx / bw;
    int ix = idx - iy * bw;
    F3 v = eval0(im, op0, s0, mean0, bx0 + ix, by0 + iy);
    lds[idx*3 + 0] = v.x; lds[idx*3 + 1] = v.y; lds[idx*3 + 2] = v.z;
  }
  __syncthreads();

  // ---- layer-1 from LDS; thread covers 4 consecutive x pixels of one row ----
  int row = threadIdx.x >> 4;
  int xbase = tx0 + ((threadIdx.x & 15) << 2);
  int y = ty0 + row;
  float f1 = (s1 > 0.f) ? ENHF : INVENHF;
  F3 res[4];
  #pragma unroll
  for (int q = 0; q < 4; q++){
    int x = xbase + q;
    F3 o;
    if (op1 < 5){
      float fx = (float)x - CXF, fy = (float)y - CYF;
      float xi = a1*fx + b1*fy + txx + CXF;
      float yi = c1*fx + d1*fy + tyy + CYF;
      float xf0 = floorf(xi), yf0 = floorf(yi);
      float wx = xi - xf0, wy = yi - yf0;
      o = mk3(0.f);
      #pragma unroll
      for (int ci = 0; ci < 4; ci++){
        int dx = ci & 1, dy = ci >> 1;
        float xx = xf0 + (float)dx, yy = yf0 + (float)dy;
        float w = (dx ? wx : (1.f - wx)) * (dy ? wy : (1.f - wy));
        F3 v;
        if (xx >= 0.f && xx <= (float)(IMW-1) && yy >= 0.f && yy <= (float)(IMH-1)){
          int li = (((int)yy - by0) * bw + ((int)xx - bx0)) * 3;
          v.x = lds[li]; v.y = lds[li+1]; v.z = lds[li+2];
        } else v = mk3(FILLF);
        o.x += w * v.x; o.y += w * v.y; o.z += w * v.z;
      }
    } else {
      int li0 = ((y - by0) * bw + (x - bx0)) * 3;
      F3 v; v.x = lds[li0]; v.y = lds[li0+1]; v.z = lds[li0+2];
      if (op1 == 5){
        o.x = f1*v.x; o.y = f1*v.y; o.z = f1*v.z;
        o = clip01(o);
      } else if (op1 == 6){
        o.x = mean1 + f1*(v.x - mean1);
        o.y = mean1 + f1*(v.y - mean1);
        o.z = mean1 + f1*(v.z - mean1);
        o = clip01(o);
      } else {  // sharpness over layer-0 output, taps from LDS (edge-clamped)
        F3 sm; sm.x = (5.f/13.f)*v.x; sm.y = (5.f/13.f)*v.y; sm.z = (5.f/13.f)*v.z;
        #pragma unroll
        for (int dy = -1; dy <= 1; dy++){
          #pragma unroll
          for (int dx = -1; dx <= 1; dx++){
            if (dx == 0 && dy == 0) continue;
            int yy = min(max(y + dy, 0), IMH-1);
            int xx = min(max(x + dx, 0), IMW-1);
            int li = ((yy - by0) * bw + (xx - bx0)) * 3;
            sm.x += (1.f/13.f)*lds[li];
            sm.y += (1.f/13.f)*lds[li+1];
            sm.z += (1.f/13.f)*lds[li+2];
          }
        }
        o.x = sm.x + f1*(v.x - sm.x);
        o.y = sm.y + f1*(v.y - sm.y);
        o.z = sm.z + f1*(v.z - sm.z);
        o = clip01(o);
      }
    }
    res[q] = o;
  }

  // packed coalesced store: 4 px = 12 floats = 3 float4 (48B-aligned base)
  float4 o0 = make_float4(res[0].x, res[0].y, res[0].z, res[1].x);
  float4 o1 = make_float4(res[1].y, res[1].z, res[2].x, res[2].y);
  float4 o2 = make_float4(res[2].z, res[3].x, res[3].y, res[3].z);
  float4* op = (float4*)(out + ((size_t)img * NPIX + (size_t)y * IMW + xbase) * 3);
  op[0] = o0; op[1] = o1; op[2] = o2;
}

extern "C" void kernel_launch(void* const* d_in, const int* in_sizes, int n_in,
                              void* d_out, int out_size, void* d_ws, size_t ws_size,
                              hipStream_t stream){
  const float* images = (const float*)d_in[0];
  const int*   ops    = (const int*)d_in[1];
  const int*   signs  = (const int*)d_in[2];
  float* out   = (float*)d_out;
  float* means = (float*)d_ws;   // 2 floats per image: [mean0, mean1]

  hipMemsetAsync(means, 0, 2*NIMG*sizeof(float), stream);
  mean0_kernel<<<NIMG*MBPI, 256, 0, stream>>>(images, ops, means);
  mean1_kernel<<<NIMG*MBPI, 256, 0, stream>>>(images, ops, signs, means);
  apply_kernel<<<NIMG*256, 256, 0, stream>>>(images, ops, signs, means, out);
}